// Round 2
// baseline (95.683 us; speedup 1.0000x reference)
//
#include <hip/hip_runtime.h>
#include <hip/hip_bf16.h>

// Problem: B=16, L=128, D=128, VOCAB=30000, OUT=10. Inputs f32, output f32
// (reference returns float32; harness compares against bf16-rounded ref).
//
// ws layout (floats):
//   Weff   [2][128*128]        @ 0        (W_dw1_eff, W_du1_eff)
//   W4     [128][512]          @ 32768    (combined [A1 | W_dw2 | R | Sm])
//   bias4  [512]               @ 98304
//   pqrs   [16*128][512]       @ 98816    (h overlays this after K4)
//   sent   [16*128][128]       @ 1147392
// peak 1409536 floats = 5.64 MB

#define LOG2E2 2.8853900817779268f  // 2*log2(e)

// K1: Weff[m][j][k] = sum_i W[(i*128+j)*128+k]   (m=0: W_dw1, m=1: W_du1)
__global__ __launch_bounds__(128) void k1_eff(const float* __restrict__ Wdw1,
                                              const float* __restrict__ Wdu1,
                                              float* __restrict__ Weff) {
    int m = blockIdx.x >> 7;
    int j = blockIdx.x & 127;
    int k = threadIdx.x;
    const float* src = m ? Wdu1 : Wdw1;
    float acc = 0.f;
    #pragma unroll 4
    for (int i = 0; i < 128; ++i)
        acc += src[i * 16384 + j * 128 + k];
    Weff[m * 16384 + j * 128 + k] = acc;
}

// K2: W4 = [Weff1 | Wdw2 | Weff2 + Weff1@Wdu2 | Wdw2@Wdu2], bias4 likewise.
__global__ __launch_bounds__(128) void k2_w4(const float* __restrict__ Weff,
                                             const float* __restrict__ Wdw2,
                                             const float* __restrict__ Wdu2,
                                             const float* __restrict__ bdw1,
                                             const float* __restrict__ bdw2,
                                             const float* __restrict__ bdu1,
                                             const float* __restrict__ bdu2,
                                             float* __restrict__ W4,
                                             float* __restrict__ bias4) {
    __shared__ float w1row[128], w2row[128];
    int j = blockIdx.x;
    int c = threadIdx.x;
    const float* Weff1 = Weff;
    const float* Weff2 = Weff + 16384;
    w1row[c] = Weff1[j * 128 + c];
    w2row[c] = Wdw2[j * 128 + c];
    __syncthreads();
    float accR = Weff2[j * 128 + c];
    float accS = 0.f;
    #pragma unroll 4
    for (int k = 0; k < 128; ++k) {
        float wd = Wdu2[k * 128 + c];
        accR += w1row[k] * wd;
        accS += w2row[k] * wd;
    }
    W4[j * 512 + c]       = w1row[c];
    W4[j * 512 + 128 + c] = w2row[c];
    W4[j * 512 + 256 + c] = accR;
    W4[j * 512 + 384 + c] = accS;
    if (j == 0) {
        float br = bdu1[c], bs = bdu2[c];
        for (int k = 0; k < 128; ++k) {
            float wd = Wdu2[k * 128 + c];
            br += bdw1[k] * wd;
            bs += bdw2[k] * wd;
        }
        bias4[c]       = bdw1[c];
        bias4[128 + c] = bdw2[c];
        bias4[256 + c] = br;
        bias4[384 + c] = bs;
    }
}

// K3: pqrs[b,l,0:512] = e[b,l,:] @ W4 + bias4, e gathered on the fly.
// Block = (b, 8-row chunk of L). 256 threads: c1=t, c2=t+256.
__global__ __launch_bounds__(256) void k3_pqrs(const int* __restrict__ word,
                                               const int* __restrict__ pos,
                                               const float* __restrict__ wemb,
                                               const float* __restrict__ pemb,
                                               const float* __restrict__ W4,
                                               const float* __restrict__ bias4,
                                               float* __restrict__ pqrs) {
    __shared__ float eT[128][8];   // [d][ll]
    int b = blockIdx.x >> 4;
    int l0 = (blockIdx.x & 15) << 3;
    for (int idx = threadIdx.x; idx < 1024; idx += 256) {
        int ll = idx >> 7, d = idx & 127;
        int l = l0 + ll;
        int wid = word[b * 128 + l];
        int pid = pos[b * 128 + l];
        eT[d][ll] = wemb[wid * 128 + d] + pemb[pid * 128 + d];
    }
    __syncthreads();
    int c1 = threadIdx.x, c2 = threadIdx.x + 256;
    float acc1[8] = {0,0,0,0,0,0,0,0};
    float acc2[8] = {0,0,0,0,0,0,0,0};
    for (int d = 0; d < 128; ++d) {
        float wa = W4[d * 512 + c1];
        float wb = W4[d * 512 + c2];
        float4 e0 = *(const float4*)&eT[d][0];
        float4 e1 = *(const float4*)&eT[d][4];
        acc1[0] += e0.x * wa; acc1[1] += e0.y * wa;
        acc1[2] += e0.z * wa; acc1[3] += e0.w * wa;
        acc1[4] += e1.x * wa; acc1[5] += e1.y * wa;
        acc1[6] += e1.z * wa; acc1[7] += e1.w * wa;
        acc2[0] += e0.x * wb; acc2[1] += e0.y * wb;
        acc2[2] += e0.z * wb; acc2[3] += e0.w * wb;
        acc2[4] += e1.x * wb; acc2[5] += e1.y * wb;
        acc2[6] += e1.z * wb; acc2[7] += e1.w * wb;
    }
    float ba = bias4[c1], bb = bias4[c2];
    #pragma unroll
    for (int ll = 0; ll < 8; ++ll) {
        int row = (b * 128 + l0 + ll) * 512;
        pqrs[row + c1] = acc1[ll] + ba;
        pqrs[row + c2] = acc2[ll] + bb;
    }
}

// K4: sent[b,i,d] = sum_j tanh(r_i + s_j) * (p_i + q_j).
// Block = (b, 8-wide d chunk). LDS holds (q, s*2log2e) for all 128 j.
__global__ __launch_bounds__(256) void k4_sent(const float* __restrict__ pqrs,
                                               float* __restrict__ sent) {
    __shared__ float2 qs[128][8];  // .x = q, .y = s * 2log2e
    int b = blockIdx.x >> 4;
    int d0 = (blockIdx.x & 15) << 3;
    for (int idx = threadIdx.x; idx < 2048; idx += 256) {
        int which = idx >> 10;
        int j = (idx >> 3) & 127;
        int dl = idx & 7;
        float v = pqrs[(b * 128 + j) * 512 + (which ? 384 : 128) + d0 + dl];
        if (which) qs[j][dl].y = v * LOG2E2;
        else       qs[j][dl].x = v;
    }
    __syncthreads();
    int dl = threadIdx.x & 7;
    int ii = threadIdx.x >> 3;  // 0..31
    #pragma unroll
    for (int il = 0; il < 4; ++il) {
        int i = il * 32 + ii;
        int base = (b * 128 + i) * 512 + d0 + dl;
        float p_i = pqrs[base];
        float rC  = pqrs[base + 256] * LOG2E2;
        float acc = 0.f;
        #pragma unroll 4
        for (int j = 0; j < 128; ++j) {
            float2 v = qs[j][dl];
            float t1 = __builtin_amdgcn_exp2f(rC + v.y);         // e^{2(r+s)}
            float th = 1.f - 2.f * __builtin_amdgcn_rcpf(t1 + 1.f);  // tanh
            acc += th * (p_i + v.x);
        }
        sent[(b * 128 + i) * 128 + d0 + dl] = acc;
    }
}

// K5: h = relu(sent @ W_d4 + b_d4). Block = (b, 16-row chunk of L).
__global__ __launch_bounds__(256) void k5_d4(const float* __restrict__ sent,
                                             const float* __restrict__ Wd4,
                                             const float* __restrict__ bd4,
                                             float* __restrict__ h) {
    __shared__ float eT[128][16];  // [d][ll]
    int b = blockIdx.x >> 3;
    int l0 = (blockIdx.x & 7) << 4;
    for (int idx = threadIdx.x; idx < 2048; idx += 256) {
        int ll = idx >> 7, d = idx & 127;
        eT[d][ll] = sent[(b * 128 + l0 + ll) * 128 + d];
    }
    __syncthreads();
    int c = threadIdx.x & 127;
    int half = threadIdx.x >> 7;   // handles ll = half*8 + m
    float acc[8] = {0,0,0,0,0,0,0,0};
    for (int d = 0; d < 128; ++d) {
        float w = Wd4[d * 128 + c];
        float4 e0 = *(const float4*)&eT[d][half * 8];
        float4 e1 = *(const float4*)&eT[d][half * 8 + 4];
        acc[0] += e0.x * w; acc[1] += e0.y * w;
        acc[2] += e0.z * w; acc[3] += e0.w * w;
        acc[4] += e1.x * w; acc[5] += e1.y * w;
        acc[6] += e1.z * w; acc[7] += e1.w * w;
    }
    float bv = bd4[c];
    #pragma unroll
    for (int m = 0; m < 8; ++m) {
        int ll = half * 8 + m;
        h[(b * 128 + l0 + ll) * 128 + c] = fmaxf(acc[m] + bv, 0.f);
    }
}

// K6: out[b,o] = sum_k h[b,k] * W_d5[k,o]  (k over 16384, o over 10). f32 out.
__global__ __launch_bounds__(256) void k6_out(const float* __restrict__ h,
                                              const float* __restrict__ Wd5,
                                              float* __restrict__ out) {
    int b = blockIdx.x;
    float acc[10] = {0,0,0,0,0,0,0,0,0,0};
    for (int k = threadIdx.x; k < 16384; k += 256) {
        float hv = h[b * 16384 + k];
        #pragma unroll
        for (int o = 0; o < 10; ++o)
            acc[o] += hv * Wd5[k * 10 + o];
    }
    #pragma unroll
    for (int o = 0; o < 10; ++o)
        #pragma unroll
        for (int s = 32; s > 0; s >>= 1)
            acc[o] += __shfl_down(acc[o], s, 64);
    __shared__ float wred[4][10];
    int lane = threadIdx.x & 63, w = threadIdx.x >> 6;
    if (lane == 0) {
        #pragma unroll
        for (int o = 0; o < 10; ++o) wred[w][o] = acc[o];
    }
    __syncthreads();
    if (threadIdx.x < 10) {
        float v = wred[0][threadIdx.x] + wred[1][threadIdx.x] +
                  wred[2][threadIdx.x] + wred[3][threadIdx.x];
        out[b * 10 + threadIdx.x] = v;
    }
}

extern "C" void kernel_launch(void* const* d_in, const int* in_sizes, int n_in,
                              void* d_out, int out_size, void* d_ws, size_t ws_size,
                              hipStream_t stream) {
    const int*   word = (const int*)d_in[0];
    const int*   pos  = (const int*)d_in[1];
    // d_in[2] = sentence_length (unused by reference)
    const float* wemb = (const float*)d_in[3];
    const float* pemb = (const float*)d_in[4];
    const float* Wdw1 = (const float*)d_in[5];
    const float* bdw1 = (const float*)d_in[6];
    const float* Wdw2 = (const float*)d_in[7];
    const float* bdw2 = (const float*)d_in[8];
    const float* Wdu1 = (const float*)d_in[9];
    const float* bdu1 = (const float*)d_in[10];
    const float* Wdu2 = (const float*)d_in[11];
    const float* bdu2 = (const float*)d_in[12];
    const float* Wd4  = (const float*)d_in[13];
    const float* bd4  = (const float*)d_in[14];
    const float* Wd5  = (const float*)d_in[15];

    float* ws    = (float*)d_ws;
    float* Weff  = ws;                 // 2*16384
    float* W4    = ws + 32768;         // 65536
    float* bias4 = ws + 98304;         // 512
    float* pqrs  = ws + 98816;         // 1048576
    float* sent  = ws + 1147392;       // 262144
    float* h     = pqrs;               // overlay: pqrs dead after K4
    float* out   = (float*)d_out;

    k1_eff <<<256, 128, 0, stream>>>(Wdw1, Wdu1, Weff);
    k2_w4  <<<128, 128, 0, stream>>>(Weff, Wdw2, Wdu2, bdw1, bdw2, bdu1, bdu2, W4, bias4);
    k3_pqrs<<<256, 256, 0, stream>>>(word, pos, wemb, pemb, W4, bias4, pqrs);
    k4_sent<<<256, 256, 0, stream>>>(pqrs, sent);
    k5_d4  <<<128, 256, 0, stream>>>(sent, Wd4, bd4, h);
    k6_out <<<16,  256, 0, stream>>>(h, Wd5, out);
}

// Round 3
// 66.471 us; speedup vs baseline: 1.4395x; 1.4395x over previous
//
#include <hip/hip_runtime.h>
#include <hip/hip_bf16.h>

// Problem: B=16, L=128, D=128, VOCAB=30000, OUT=10. Inputs f32, output f32.
//
// ws layout (floats):
//   Weff   [2][128*128]        @ 0
//   W4     [128][512]          @ 32768    ([Wdw1_eff | Wdw2 | R | Sm])
//   bias4  [512]               @ 98304
//   pqrs   [16*128][512]       @ 98816    (h overlays this after K4)
//   sent   [16*128][128]       @ 1147392
// peak 1409536 floats = 5.64 MB

#define LOG2E2 2.8853900817779268f  // 2*log2(e)

// K1: Weff[m][j][k] = sum_i W[(i*128+j)*128+k]. Grid 256 = (2m x 128j),
// 512 threads: 4 i-quarters x 128 k, 32 serial loads each, LDS reduce.
__global__ __launch_bounds__(512) void k1_eff(const float* __restrict__ Wdw1,
                                              const float* __restrict__ Wdu1,
                                              float* __restrict__ Weff) {
    __shared__ float red[4][128];
    int m = blockIdx.x >> 7;
    int j = blockIdx.x & 127;
    int i4 = threadIdx.x >> 7;
    int k = threadIdx.x & 127;
    const float* src = (m ? Wdu1 : Wdw1) + (size_t)i4 * 32 * 16384 + j * 128 + k;
    float acc = 0.f;
    #pragma unroll 8
    for (int i = 0; i < 32; ++i)
        acc += src[(size_t)i * 16384];
    red[i4][k] = acc;
    __syncthreads();
    if (i4 == 0)
        Weff[m * 16384 + j * 128 + k] = red[0][k] + red[1][k] + red[2][k] + red[3][k];
}

// K2: W4 = [Weff1 | Wdw2 | Weff2 + Weff1@Wdu2 | Wdw2@Wdu2], bias4 likewise.
// Grid 128 (j), 256 threads: which = tid>>7 (0: R-part, 1: S-part), c = tid&127.
__global__ __launch_bounds__(256) void k2_w4(const float* __restrict__ Weff,
                                             const float* __restrict__ Wdw2,
                                             const float* __restrict__ Wdu2,
                                             const float* __restrict__ bdw1,
                                             const float* __restrict__ bdw2,
                                             const float* __restrict__ bdu1,
                                             const float* __restrict__ bdu2,
                                             float* __restrict__ W4,
                                             float* __restrict__ bias4) {
    __shared__ float w1row[128], w2row[128];
    int j = blockIdx.x;
    int c = threadIdx.x & 127;
    int which = threadIdx.x >> 7;
    if (which == 0) w1row[c] = Weff[j * 128 + c];
    else            w2row[c] = Wdw2[j * 128 + c];
    __syncthreads();
    const float* srow = which ? w2row : w1row;
    float acc = which ? 0.f : Weff[16384 + j * 128 + c];
    #pragma unroll 4
    for (int k = 0; k < 128; ++k)
        acc += srow[k] * Wdu2[k * 128 + c];
    if (which == 0) {
        W4[j * 512 + c]       = w1row[c];
        W4[j * 512 + 256 + c] = acc;
    } else {
        W4[j * 512 + 128 + c] = w2row[c];
        W4[j * 512 + 384 + c] = acc;
    }
    if (j == 0) {
        const float* bsrc = which ? bdw2 : bdw1;
        float bacc = which ? bdu2[c] : bdu1[c];
        for (int k = 0; k < 128; ++k)
            bacc += bsrc[k] * Wdu2[k * 128 + c];
        if (which == 0) { bias4[c] = bdw1[c];       bias4[256 + c] = bacc; }
        else            { bias4[128 + c] = bdw2[c]; bias4[384 + c] = bacc; }
    }
}

// K3: pqrs[b,l,:] = e[b,l,:] @ W4 + bias4. Grid 256 = (16b x 16 chunks of 8
// rows), 512 threads: one output column c each, 8 rows.
__global__ __launch_bounds__(512) void k3_pqrs(const int* __restrict__ word,
                                               const int* __restrict__ pos,
                                               const float* __restrict__ wemb,
                                               const float* __restrict__ pemb,
                                               const float* __restrict__ W4,
                                               const float* __restrict__ bias4,
                                               float* __restrict__ pqrs) {
    __shared__ float eT[128][8];   // [d][ll]
    int b = blockIdx.x >> 4;
    int l0 = (blockIdx.x & 15) << 3;
    for (int idx = threadIdx.x; idx < 1024; idx += 512) {
        int ll = idx >> 7, d = idx & 127;
        int l = l0 + ll;
        int wid = word[b * 128 + l];
        int pid = pos[b * 128 + l];
        eT[d][ll] = wemb[wid * 128 + d] + pemb[pid * 128 + d];
    }
    __syncthreads();
    int c = threadIdx.x;
    float acc[8] = {0,0,0,0,0,0,0,0};
    for (int d = 0; d < 128; ++d) {
        float w = W4[d * 512 + c];
        float4 e0 = *(const float4*)&eT[d][0];
        float4 e1 = *(const float4*)&eT[d][4];
        acc[0] += e0.x * w; acc[1] += e0.y * w;
        acc[2] += e0.z * w; acc[3] += e0.w * w;
        acc[4] += e1.x * w; acc[5] += e1.y * w;
        acc[6] += e1.z * w; acc[7] += e1.w * w;
    }
    float bv = bias4[c];
    #pragma unroll
    for (int ll = 0; ll < 8; ++ll)
        pqrs[(b * 128 + l0 + ll) * 512 + c] = acc[ll] + bv;
}

// K4: sent[b,i,d] = sum_j tanh(r_i + s_j) * (p_i + q_j)
//   tanh(r+s) = 1 - 2/(Er*Ej + 1), Er = exp2(2log2e*r), Ej = exp2(2log2e*s).
// Grid 1024 = (16b x 4 i-chunks x 16 d-chunks), 256 threads = 32 i x 8 d.
__global__ __launch_bounds__(256) void k4_sent(const float* __restrict__ pqrs,
                                               float* __restrict__ sent) {
    __shared__ float2 qe[128][8];  // .x = q_j, .y = Ej
    int b  = blockIdx.x >> 6;
    int i0 = ((blockIdx.x >> 4) & 3) << 5;
    int d0 = (blockIdx.x & 15) << 3;
    for (int idx = threadIdx.x; idx < 2048; idx += 256) {
        int which = idx >> 10;
        int j = (idx >> 3) & 127;
        int dl = idx & 7;
        float v = pqrs[(b * 128 + j) * 512 + (which ? 384 : 128) + d0 + dl];
        if (which) qe[j][dl].y = __builtin_amdgcn_exp2f(v * LOG2E2);
        else       qe[j][dl].x = v;
    }
    __syncthreads();
    int dl = threadIdx.x & 7;
    int ii = threadIdx.x >> 3;  // 0..31
    int i = i0 + ii;
    int base = (b * 128 + i) * 512 + d0 + dl;
    float p_i = pqrs[base];
    float Er  = __builtin_amdgcn_exp2f(pqrs[base + 256] * LOG2E2);
    float acc = 0.f;
    #pragma unroll 8
    for (int j = 0; j < 128; ++j) {
        float2 v = qe[j][dl];
        float t1 = Er * v.y;                                 // e^{2(r+s)}
        float th = 1.f - 2.f * __builtin_amdgcn_rcpf(t1 + 1.f);
        acc += th * (p_i + v.x);
    }
    sent[(b * 128 + i) * 128 + d0 + dl] = acc;
}

// K5: h = relu(sent @ W_d4 + b_d4). Grid 256 = (16b x 16 chunks of 8 rows),
// 512 threads: c = tid&127, quarter q = tid>>7 handles rows 2q, 2q+1.
__global__ __launch_bounds__(512) void k5_d4(const float* __restrict__ sent,
                                             const float* __restrict__ Wd4,
                                             const float* __restrict__ bd4,
                                             float* __restrict__ h) {
    __shared__ float eT[128][8];  // [d][ll]
    int b = blockIdx.x >> 4;
    int l0 = (blockIdx.x & 15) << 3;
    for (int idx = threadIdx.x; idx < 1024; idx += 512) {
        int ll = idx >> 7, d = idx & 127;
        eT[d][ll] = sent[(b * 128 + l0 + ll) * 128 + d];
    }
    __syncthreads();
    int c = threadIdx.x & 127;
    int q = threadIdx.x >> 7;
    float a0 = 0.f, a1 = 0.f;
    #pragma unroll 4
    for (int d = 0; d < 128; ++d) {
        float w = Wd4[d * 128 + c];
        float2 e = *(const float2*)&eT[d][q * 2];
        a0 += e.x * w;
        a1 += e.y * w;
    }
    float bv = bd4[c];
    h[(b * 128 + l0 + q * 2) * 128 + c]     = fmaxf(a0 + bv, 0.f);
    h[(b * 128 + l0 + q * 2 + 1) * 128 + c] = fmaxf(a1 + bv, 0.f);
}

// K6: out[b,:] = h[b,:] @ W_d5. Grid 16 (b), 1024 threads, 16 k-iters each.
__global__ __launch_bounds__(1024) void k6_out(const float* __restrict__ h,
                                               const float* __restrict__ Wd5,
                                               float* __restrict__ out) {
    int b = blockIdx.x;
    float acc[10] = {0,0,0,0,0,0,0,0,0,0};
    for (int it = 0; it < 16; ++it) {
        int k = threadIdx.x + it * 1024;
        float hv = h[b * 16384 + k];
        const float2* w2 = (const float2*)(Wd5 + (size_t)k * 10);
        float2 w0 = w2[0], w1 = w2[1], w4 = w2[2], w6 = w2[3], w8 = w2[4];
        acc[0] += hv * w0.x; acc[1] += hv * w0.y;
        acc[2] += hv * w1.x; acc[3] += hv * w1.y;
        acc[4] += hv * w4.x; acc[5] += hv * w4.y;
        acc[6] += hv * w6.x; acc[7] += hv * w6.y;
        acc[8] += hv * w8.x; acc[9] += hv * w8.y;
    }
    #pragma unroll
    for (int o = 0; o < 10; ++o)
        #pragma unroll
        for (int s = 32; s > 0; s >>= 1)
            acc[o] += __shfl_down(acc[o], s, 64);
    __shared__ float wred[16][10];
    int lane = threadIdx.x & 63, w = threadIdx.x >> 6;
    if (lane == 0) {
        #pragma unroll
        for (int o = 0; o < 10; ++o) wred[w][o] = acc[o];
    }
    __syncthreads();
    if (threadIdx.x < 10) {
        float v = 0.f;
        #pragma unroll
        for (int ww = 0; ww < 16; ++ww) v += wred[ww][threadIdx.x];
        out[b * 10 + threadIdx.x] = v;
    }
}

extern "C" void kernel_launch(void* const* d_in, const int* in_sizes, int n_in,
                              void* d_out, int out_size, void* d_ws, size_t ws_size,
                              hipStream_t stream) {
    const int*   word = (const int*)d_in[0];
    const int*   pos  = (const int*)d_in[1];
    // d_in[2] = sentence_length (unused by reference)
    const float* wemb = (const float*)d_in[3];
    const float* pemb = (const float*)d_in[4];
    const float* Wdw1 = (const float*)d_in[5];
    const float* bdw1 = (const float*)d_in[6];
    const float* Wdw2 = (const float*)d_in[7];
    const float* bdw2 = (const float*)d_in[8];
    const float* Wdu1 = (const float*)d_in[9];
    const float* bdu1 = (const float*)d_in[10];
    const float* Wdu2 = (const float*)d_in[11];
    const float* bdu2 = (const float*)d_in[12];
    const float* Wd4  = (const float*)d_in[13];
    const float* bd4  = (const float*)d_in[14];
    const float* Wd5  = (const float*)d_in[15];

    float* ws    = (float*)d_ws;
    float* Weff  = ws;                 // 2*16384
    float* W4    = ws + 32768;         // 65536
    float* bias4 = ws + 98304;         // 512
    float* pqrs  = ws + 98816;         // 1048576
    float* sent  = ws + 1147392;       // 262144
    float* h     = pqrs;               // overlay: pqrs dead after K4
    float* out   = (float*)d_out;

    k1_eff <<<256,  512, 0, stream>>>(Wdw1, Wdu1, Weff);
    k2_w4  <<<128,  256, 0, stream>>>(Weff, Wdw2, Wdu2, bdw1, bdw2, bdu1, bdu2, W4, bias4);
    k3_pqrs<<<256,  512, 0, stream>>>(word, pos, wemb, pemb, W4, bias4, pqrs);
    k4_sent<<<1024, 256, 0, stream>>>(pqrs, sent);
    k5_d4  <<<256,  512, 0, stream>>>(sent, Wd4, bd4, h);
    k6_out <<<16,  1024, 0, stream>>>(h, Wd5, out);
}

// Round 4
// 55.361 us; speedup vs baseline: 1.7284x; 1.2007x over previous
//
#include <hip/hip_runtime.h>
#include <hip/hip_bf16.h>

// Problem: B=16, L=128, D=128, VOCAB=30000, OUT=10. Inputs f32, output f32.
//
// ws layout (floats):
//   Weff   [2][128*128]        @ 0
//   W4     [128][512]          @ 32768    ([Wdw1_eff | Wdw2 | R | Sm])
//   bias4  [512]               @ 98304
//   pqrs   [16*128][512]       @ 98816
//   sent   [16*128][128]       @ 1147392
// peak 1409536 floats = 5.64 MB
//
// Pipeline: K1 (Weff + zero d_out) -> K2 (W4) -> K3 (pqrs) -> K4 (sent)
//           -> K5 (d4+relu+d5 projection, atomicAdd into d_out)

#define LOG2E2 2.8853900817779268f  // 2*log2(e)

// K1: Weff[m][j][k] = sum_i W[(i*128+j)*128+k]. Grid 256 = (2m x 128j),
// 1024 thr = 8 i-groups x 128 k; 16 fully-unrolled loads each (16MB in flight).
// Also zeroes d_out (block 0) for K5's atomics.
__global__ __launch_bounds__(1024) void k1_eff(const float* __restrict__ Wdw1,
                                               const float* __restrict__ Wdu1,
                                               float* __restrict__ Weff,
                                               float* __restrict__ out) {
    __shared__ float red[8][128];
    int m = blockIdx.x >> 7;
    int j = blockIdx.x & 127;
    int g = threadIdx.x >> 7;
    int k = threadIdx.x & 127;
    const float* src = (m ? Wdu1 : Wdw1) + (size_t)g * 16 * 16384 + j * 128 + k;
    float acc = 0.f;
    #pragma unroll
    for (int i = 0; i < 16; ++i)
        acc += src[(size_t)i * 16384];
    red[g][k] = acc;
    if (blockIdx.x == 0 && threadIdx.x < 160) out[threadIdx.x] = 0.f;
    __syncthreads();
    if (g == 0) {
        float s = 0.f;
        #pragma unroll
        for (int t = 0; t < 8; ++t) s += red[t][k];
        Weff[m * 16384 + j * 128 + k] = s;
    }
}

// K2: W4 = [Weff1 | Wdw2 | Weff2 + Weff1@Wdu2 | Wdw2@Wdu2], bias4 likewise.
__global__ __launch_bounds__(256) void k2_w4(const float* __restrict__ Weff,
                                             const float* __restrict__ Wdw2,
                                             const float* __restrict__ Wdu2,
                                             const float* __restrict__ bdw1,
                                             const float* __restrict__ bdw2,
                                             const float* __restrict__ bdu1,
                                             const float* __restrict__ bdu2,
                                             float* __restrict__ W4,
                                             float* __restrict__ bias4) {
    __shared__ float w1row[128], w2row[128];
    int j = blockIdx.x;
    int c = threadIdx.x & 127;
    int which = threadIdx.x >> 7;
    if (which == 0) w1row[c] = Weff[j * 128 + c];
    else            w2row[c] = Wdw2[j * 128 + c];
    __syncthreads();
    const float* srow = which ? w2row : w1row;
    float acc = which ? 0.f : Weff[16384 + j * 128 + c];
    #pragma unroll 4
    for (int k = 0; k < 128; ++k)
        acc += srow[k] * Wdu2[k * 128 + c];
    if (which == 0) {
        W4[j * 512 + c]       = w1row[c];
        W4[j * 512 + 256 + c] = acc;
    } else {
        W4[j * 512 + 128 + c] = w2row[c];
        W4[j * 512 + 384 + c] = acc;
    }
    if (j == 0) {
        const float* bsrc = which ? bdw2 : bdw1;
        float bacc = which ? bdu2[c] : bdu1[c];
        for (int k = 0; k < 128; ++k)
            bacc += bsrc[k] * Wdu2[k * 128 + c];
        if (which == 0) { bias4[c] = bdw1[c];       bias4[256 + c] = bacc; }
        else            { bias4[128 + c] = bdw2[c]; bias4[384 + c] = bacc; }
    }
}

// K3: pqrs[b,l,:] = e[b,l,:] @ W4 + bias4. Grid 256 = (16b x 16 chunks of 8
// rows), 512 threads: one output column c each, 8 rows.
__global__ __launch_bounds__(512) void k3_pqrs(const int* __restrict__ word,
                                               const int* __restrict__ pos,
                                               const float* __restrict__ wemb,
                                               const float* __restrict__ pemb,
                                               const float* __restrict__ W4,
                                               const float* __restrict__ bias4,
                                               float* __restrict__ pqrs) {
    __shared__ float eT[128][8];   // [d][ll]
    int b = blockIdx.x >> 4;
    int l0 = (blockIdx.x & 15) << 3;
    for (int idx = threadIdx.x; idx < 1024; idx += 512) {
        int ll = idx >> 7, d = idx & 127;
        int l = l0 + ll;
        int wid = word[b * 128 + l];
        int pid = pos[b * 128 + l];
        eT[d][ll] = wemb[wid * 128 + d] + pemb[pid * 128 + d];
    }
    __syncthreads();
    int c = threadIdx.x;
    float acc[8] = {0,0,0,0,0,0,0,0};
    for (int d = 0; d < 128; ++d) {
        float w = W4[d * 512 + c];
        float4 e0 = *(const float4*)&eT[d][0];
        float4 e1 = *(const float4*)&eT[d][4];
        acc[0] += e0.x * w; acc[1] += e0.y * w;
        acc[2] += e0.z * w; acc[3] += e0.w * w;
        acc[4] += e1.x * w; acc[5] += e1.y * w;
        acc[6] += e1.z * w; acc[7] += e1.w * w;
    }
    float bv = bias4[c];
    #pragma unroll
    for (int ll = 0; ll < 8; ++ll)
        pqrs[(b * 128 + l0 + ll) * 512 + c] = acc[ll] + bv;
}

// K4: sent[b,i,d] = sum_j tanh(r_i + s_j) * (p_i + q_j)
//   tanh = 1 - 2*rcp(fma(Er, Ej, 1)); Er/Ej = exp2(2log2e * r/s).
// Grid 512 = (16b x 2 i-chunks(64) x 16 d-chunks(8)), 256 thr = 32 ii x 8 dl,
// 2 i-outputs per thread (halves LDS issue), 2 blocks/CU.
__global__ __launch_bounds__(256) void k4_sent(const float* __restrict__ pqrs,
                                               float* __restrict__ sent) {
    __shared__ float2 qe[128][8];  // .x = q_j, .y = Ej
    int b  = blockIdx.x >> 5;
    int i0 = ((blockIdx.x >> 4) & 1) << 6;
    int d0 = (blockIdx.x & 15) << 3;
    for (int idx = threadIdx.x; idx < 2048; idx += 256) {
        int which = idx >> 10;
        int j = (idx >> 3) & 127;
        int dl = idx & 7;
        float v = pqrs[(b * 128 + j) * 512 + (which ? 384 : 128) + d0 + dl];
        if (which) qe[j][dl].y = __builtin_amdgcn_exp2f(v * LOG2E2);
        else       qe[j][dl].x = v;
    }
    __syncthreads();
    int dl = threadIdx.x & 7;
    int ii = threadIdx.x >> 3;  // 0..31
    int iA = i0 + ii, iB = i0 + ii + 32;
    int baseA = (b * 128 + iA) * 512 + d0 + dl;
    int baseB = (b * 128 + iB) * 512 + d0 + dl;
    float pA = pqrs[baseA];
    float pB = pqrs[baseB];
    float ErA = __builtin_amdgcn_exp2f(pqrs[baseA + 256] * LOG2E2);
    float ErB = __builtin_amdgcn_exp2f(pqrs[baseB + 256] * LOG2E2);
    float accA = 0.f, accB = 0.f;
    #pragma unroll 8
    for (int j = 0; j < 128; ++j) {
        float2 v = qe[j][dl];
        float tA = fmaf(ErA, v.y, 1.f);
        float tB = fmaf(ErB, v.y, 1.f);
        float gA = __builtin_amdgcn_rcpf(tA);
        float gB = __builtin_amdgcn_rcpf(tB);
        float uA = pA + v.x;
        float uB = pB + v.x;
        float thA = fmaf(-2.f, gA, 1.f);
        float thB = fmaf(-2.f, gB, 1.f);
        accA = fmaf(thA, uA, accA);
        accB = fmaf(thB, uB, accB);
    }
    sent[(b * 128 + iA) * 128 + d0 + dl] = accA;
    sent[(b * 128 + iB) * 128 + d0 + dl] = accB;
}

// K5: h = relu(sent @ W_d4 + b_d4) kept in registers; project onto W_d5 and
// atomicAdd 10 partials into out[b,:]. Grid 256 = (16b x 16 l-chunks of 8),
// 512 thr: c = tid&127, q = tid>>7 handles rows 2q, 2q+1.
__global__ __launch_bounds__(512) void k5_out(const float* __restrict__ sent,
                                              const float* __restrict__ Wd4,
                                              const float* __restrict__ bd4,
                                              const float* __restrict__ Wd5,
                                              float* __restrict__ out) {
    __shared__ float eT[128][8];  // [d][ll]
    int b = blockIdx.x >> 4;
    int l0 = (blockIdx.x & 15) << 3;
    for (int idx = threadIdx.x; idx < 1024; idx += 512) {
        int ll = idx >> 7, d = idx & 127;
        eT[d][ll] = sent[(b * 128 + l0 + ll) * 128 + d];
    }
    __syncthreads();
    int c = threadIdx.x & 127;
    int q = threadIdx.x >> 7;
    float a0 = 0.f, a1 = 0.f;
    #pragma unroll 4
    for (int d = 0; d < 128; ++d) {
        float w = Wd4[d * 128 + c];
        float2 e = *(const float2*)&eT[d][q * 2];
        a0 += e.x * w;
        a1 += e.y * w;
    }
    float bv = bd4[c];
    a0 = fmaxf(a0 + bv, 0.f);
    a1 = fmaxf(a1 + bv, 0.f);
    int lA = l0 + q * 2, lB = lA + 1;
    const float* w5a = Wd5 + ((size_t)(lA * 128 + c)) * 10;
    const float* w5b = Wd5 + ((size_t)(lB * 128 + c)) * 10;
    float acc[10];
    #pragma unroll
    for (int o = 0; o < 10; ++o)
        acc[o] = a0 * w5a[o] + a1 * w5b[o];
    #pragma unroll
    for (int o = 0; o < 10; ++o)
        #pragma unroll
        for (int s = 32; s > 0; s >>= 1)
            acc[o] += __shfl_down(acc[o], s, 64);
    __shared__ float wred[8][10];
    int lane = threadIdx.x & 63, w = threadIdx.x >> 6;
    if (lane == 0) {
        #pragma unroll
        for (int o = 0; o < 10; ++o) wred[w][o] = acc[o];
    }
    __syncthreads();
    if (threadIdx.x < 10) {
        float v = 0.f;
        #pragma unroll
        for (int ww = 0; ww < 8; ++ww) v += wred[ww][threadIdx.x];
        atomicAdd(&out[b * 10 + threadIdx.x], v);
    }
}

extern "C" void kernel_launch(void* const* d_in, const int* in_sizes, int n_in,
                              void* d_out, int out_size, void* d_ws, size_t ws_size,
                              hipStream_t stream) {
    const int*   word = (const int*)d_in[0];
    const int*   pos  = (const int*)d_in[1];
    // d_in[2] = sentence_length (unused by reference)
    const float* wemb = (const float*)d_in[3];
    const float* pemb = (const float*)d_in[4];
    const float* Wdw1 = (const float*)d_in[5];
    const float* bdw1 = (const float*)d_in[6];
    const float* Wdw2 = (const float*)d_in[7];
    const float* bdw2 = (const float*)d_in[8];
    const float* Wdu1 = (const float*)d_in[9];
    const float* bdu1 = (const float*)d_in[10];
    const float* Wdu2 = (const float*)d_in[11];
    const float* bdu2 = (const float*)d_in[12];
    const float* Wd4  = (const float*)d_in[13];
    const float* bd4  = (const float*)d_in[14];
    const float* Wd5  = (const float*)d_in[15];

    float* ws    = (float*)d_ws;
    float* Weff  = ws;                 // 2*16384
    float* W4    = ws + 32768;         // 65536
    float* bias4 = ws + 98304;         // 512
    float* pqrs  = ws + 98816;         // 1048576
    float* sent  = ws + 1147392;       // 262144
    float* out   = (float*)d_out;

    k1_eff <<<256, 1024, 0, stream>>>(Wdw1, Wdu1, Weff, out);
    k2_w4  <<<128,  256, 0, stream>>>(Weff, Wdw2, Wdu2, bdw1, bdw2, bdu1, bdu2, W4, bias4);
    k3_pqrs<<<256,  512, 0, stream>>>(word, pos, wemb, pemb, W4, bias4, pqrs);
    k4_sent<<<512,  256, 0, stream>>>(pqrs, sent);
    k5_out <<<256,  512, 0, stream>>>(sent, Wd4, bd4, Wd5, out);
}

// Round 5
// 45.645 us; speedup vs baseline: 2.0962x; 1.2128x over previous
//
#include <hip/hip_runtime.h>
#include <hip/hip_bf16.h>

// Problem: B=16, L=128, D=128, VOCAB=30000, OUT=10. Inputs f32, output f32.
//
// W4' is 640 cols: [c0: W1eff(p) | c1: Wdw2(q) | c2: W2eff(r part A) |
//                   c3: W1eff@Wdu2(r part B) | c4: Wdw2@Wdu2(s)]
// bias': [bdw1 | bdw2 | bdu1 | bdw1@Wdu2 | bdu2 + bdw2@Wdu2]
// r = (pqrs col2 + col3) is summed inside K4 when forming Er.
//
// ws layout (floats):
//   W4     [128][640]   @ 0
//   bias4  [640]        @ 81920
//   pqrs   [2048][640]  @ 82560
//   sent   [2048][128]  @ 1393280
// peak 1655424 floats = 6.62 MB
//
// Pipeline: K12 (row-sums + @Wdu2 + zero d_out) -> K3 (pqrs) -> K4 (sent)
//           -> K5 (d4+relu+d5, atomicAdd into d_out)

#define LOG2E2 2.8853900817779268f  // 2*log2(e)

// K12: grid 256 = (128 j x 2 m), 1024 thr.
//  m=0: w1row = sum_i Wdw1 -> W4 c0;  w1row@Wdu2 -> W4 c3; bias c0,c3.
//  m=1: w2eff = sum_i Wdu1 -> W4 c2;  Wdw2[j] -> W4 c1; Wdw2[j]@Wdu2 -> W4 c4;
//       bias c1,c2,c4.
__global__ __launch_bounds__(1024) void k12_w4(const float* __restrict__ Wdw1,
                                               const float* __restrict__ Wdu1,
                                               const float* __restrict__ Wdw2,
                                               const float* __restrict__ Wdu2,
                                               const float* __restrict__ bdw1,
                                               const float* __restrict__ bdw2,
                                               const float* __restrict__ bdu1,
                                               const float* __restrict__ bdu2,
                                               float* __restrict__ W4,
                                               float* __restrict__ bias4,
                                               float* __restrict__ out) {
    __shared__ float red[8][128];
    __shared__ float srow[128];   // matmul source row (w1row or w2row)
    int j = blockIdx.x >> 1;
    int m = blockIdx.x & 1;
    int g = threadIdx.x >> 7;     // 0..7
    int k = threadIdx.x & 127;

    // phase A: strided i-sum of the big weight matrix
    const float* src = (m ? Wdu1 : Wdw1) + (size_t)g * 16 * 16384 + j * 128 + k;
    float acc = 0.f;
    #pragma unroll
    for (int i = 0; i < 16; ++i)
        acc += src[(size_t)i * 16384];
    red[g][k] = acc;
    if (blockIdx.x == 2 && threadIdx.x < 160) out[threadIdx.x] = 0.f;
    __syncthreads();
    if (g == 0) {
        float s = 0.f;
        #pragma unroll
        for (int t = 0; t < 8; ++t) s += red[t][k];
        W4[j * 640 + (m ? 256 : 0) + k] = s;   // c2 : c0
        if (m == 0) {
            srow[k] = s;                        // w1row
        } else {
            float w2 = Wdw2[j * 128 + k];
            srow[k] = w2;                       // w2row
            W4[j * 640 + 128 + k] = w2;         // c1
        }
    }
    __syncthreads();

    // phase B: srow @ Wdu2, k-split over 8 groups
    {
        int kq = threadIdx.x >> 7;
        int c  = threadIdx.x & 127;
        float a = 0.f;
        #pragma unroll
        for (int t = 0; t < 16; ++t) {
            int kk = kq * 16 + t;
            a += srow[kk] * Wdu2[kk * 128 + c];
        }
        red[kq][c] = a;
        __syncthreads();
        if (kq == 0) {
            float tot = 0.f;
            #pragma unroll
            for (int t = 0; t < 8; ++t) tot += red[t][c];
            W4[j * 640 + (m ? 512 : 384) + c] = tot;   // c4 : c3
        }
    }

    // phase C: bias vectors (blocks with j==0 only; block-uniform branch)
    if (j == 0) {
        __syncthreads();
        int kq = threadIdx.x >> 7;
        int c  = threadIdx.x & 127;
        const float* bsrc = m ? bdw2 : bdw1;
        float a = 0.f;
        #pragma unroll
        for (int t = 0; t < 16; ++t) {
            int kk = kq * 16 + t;
            a += bsrc[kk] * Wdu2[kk * 128 + c];
        }
        red[kq][c] = a;
        __syncthreads();
        if (kq == 0) {
            float tot = 0.f;
            #pragma unroll
            for (int t = 0; t < 8; ++t) tot += red[t][c];
            if (m == 0) {
                bias4[c]       = bdw1[c];
                bias4[384 + c] = tot;              // bdw1@Wdu2
            } else {
                bias4[128 + c] = bdw2[c];
                bias4[256 + c] = bdu1[c];
                bias4[512 + c] = bdu2[c] + tot;    // bdu2 + bdw2@Wdu2
            }
        }
    }
}

// K3: pqrs[b,l,0:640] = e[b,l,:] @ W4 + bias4. Grid 256 = (16b x 16 chunks
// of 8 rows), 640 threads: one output column each, 8 rows.
__global__ __launch_bounds__(640) void k3_pqrs(const int* __restrict__ word,
                                               const int* __restrict__ pos,
                                               const float* __restrict__ wemb,
                                               const float* __restrict__ pemb,
                                               const float* __restrict__ W4,
                                               const float* __restrict__ bias4,
                                               float* __restrict__ pqrs) {
    __shared__ float eT[128][8];   // [d][ll]
    int b = blockIdx.x >> 4;
    int l0 = (blockIdx.x & 15) << 3;
    for (int idx = threadIdx.x; idx < 1024; idx += 640) {
        int ll = idx >> 7, d = idx & 127;
        int l = l0 + ll;
        int wid = word[b * 128 + l];
        int pid = pos[b * 128 + l];
        eT[d][ll] = wemb[wid * 128 + d] + pemb[pid * 128 + d];
    }
    __syncthreads();
    int c = threadIdx.x;  // 0..639
    float acc[8] = {0,0,0,0,0,0,0,0};
    for (int d = 0; d < 128; ++d) {
        float w = W4[d * 640 + c];
        float4 e0 = *(const float4*)&eT[d][0];
        float4 e1 = *(const float4*)&eT[d][4];
        acc[0] += e0.x * w; acc[1] += e0.y * w;
        acc[2] += e0.z * w; acc[3] += e0.w * w;
        acc[4] += e1.x * w; acc[5] += e1.y * w;
        acc[6] += e1.z * w; acc[7] += e1.w * w;
    }
    float bv = bias4[c];
    #pragma unroll
    for (int ll = 0; ll < 8; ++ll)
        pqrs[(size_t)(b * 128 + l0 + ll) * 640 + c] = acc[ll] + bv;
}

// K4: sent[b,i,d] = sum_j tanh(r_i+s_j)*(p_i+q_j)
//   = (128*p_i + Sq) - 2 * sum_j (p_i+q_j) * rcp(Er*Ej + 1)
//   Er = exp2(2log2e*(r1_i+r2_i)), Ej = exp2(2log2e*s_j), Sq = sum_j q_j.
// Grid 512 = (16b x 2 ih x 16 dc), 256 thr = 32 ii x 8 dl, 2 i per thread.
__global__ __launch_bounds__(256) void k4_sent(const float* __restrict__ pqrs,
                                               float* __restrict__ sent) {
    __shared__ float2 qe[128][8];  // .x = q_j, .y = Ej
    __shared__ float SqL[8];
    int b  = blockIdx.x >> 5;
    int ih = (blockIdx.x >> 4) & 1;
    int d0 = (blockIdx.x & 15) << 3;
    for (int idx = threadIdx.x; idx < 2048; idx += 256) {
        int which = idx >> 10;
        int j = (idx >> 3) & 127;
        int dl = idx & 7;
        float v = pqrs[(size_t)(b * 128 + j) * 640 + (which ? 512 : 128) + d0 + dl];
        if (which) qe[j][dl].y = __builtin_amdgcn_exp2f(v * LOG2E2);
        else       qe[j][dl].x = v;
    }
    __syncthreads();
    if (threadIdx.x < 64) {
        int dl = threadIdx.x >> 3;
        int g  = threadIdx.x & 7;
        float s = 0.f;
        #pragma unroll
        for (int t = 0; t < 16; ++t) s += qe[g * 16 + t][dl].x;
        s += __shfl_xor(s, 1, 64);
        s += __shfl_xor(s, 2, 64);
        s += __shfl_xor(s, 4, 64);
        if (g == 0) SqL[dl] = s;
    }
    __syncthreads();

    int dl = threadIdx.x & 7;
    int ii = threadIdx.x >> 3;  // 0..31
    int iA = ih * 64 + ii, iB = iA + 32;
    size_t baseA = (size_t)(b * 128 + iA) * 640 + d0 + dl;
    size_t baseB = (size_t)(b * 128 + iB) * 640 + d0 + dl;
    float pA = pqrs[baseA];
    float pB = pqrs[baseB];
    float ErA = __builtin_amdgcn_exp2f((pqrs[baseA + 256] + pqrs[baseA + 384]) * LOG2E2);
    float ErB = __builtin_amdgcn_exp2f((pqrs[baseB + 256] + pqrs[baseB + 384]) * LOG2E2);
    float accA = 0.f, accB = 0.f;
    #pragma unroll 8
    for (int j = 0; j < 128; ++j) {
        float2 v = qe[j][dl];
        float tA = fmaf(ErA, v.y, 1.f);
        float tB = fmaf(ErB, v.y, 1.f);
        float gA = __builtin_amdgcn_rcpf(tA);
        float gB = __builtin_amdgcn_rcpf(tB);
        float uA = pA + v.x;
        float uB = pB + v.x;
        accA = fmaf(uA, gA, accA);
        accB = fmaf(uB, gB, accB);
    }
    float Sq = SqL[dl];
    sent[(b * 128 + iA) * 128 + d0 + dl] = fmaf(-2.f, accA, fmaf(128.f, pA, Sq));
    sent[(b * 128 + iB) * 128 + d0 + dl] = fmaf(-2.f, accB, fmaf(128.f, pB, Sq));
}

// K5: h = relu(sent @ W_d4 + b_d4) in registers; project onto W_d5 and
// atomicAdd 10 partials into out[b,:]. Grid 256 = (16b x 16 l-chunks of 8),
// 512 thr: c = tid&127, q = tid>>7 handles rows 2q, 2q+1.
__global__ __launch_bounds__(512) void k5_out(const float* __restrict__ sent,
                                              const float* __restrict__ Wd4,
                                              const float* __restrict__ bd4,
                                              const float* __restrict__ Wd5,
                                              float* __restrict__ out) {
    __shared__ float eT[128][8];  // [d][ll]
    int b = blockIdx.x >> 4;
    int l0 = (blockIdx.x & 15) << 3;
    for (int idx = threadIdx.x; idx < 1024; idx += 512) {
        int ll = idx >> 7, d = idx & 127;
        eT[d][ll] = sent[(b * 128 + l0 + ll) * 128 + d];
    }
    __syncthreads();
    int c = threadIdx.x & 127;
    int q = threadIdx.x >> 7;
    float a0 = 0.f, a1 = 0.f;
    #pragma unroll 4
    for (int d = 0; d < 128; ++d) {
        float w = Wd4[d * 128 + c];
        float2 e = *(const float2*)&eT[d][q * 2];
        a0 += e.x * w;
        a1 += e.y * w;
    }
    float bv = bd4[c];
    a0 = fmaxf(a0 + bv, 0.f);
    a1 = fmaxf(a1 + bv, 0.f);
    int lA = l0 + q * 2, lB = lA + 1;
    const float* w5a = Wd5 + ((size_t)(lA * 128 + c)) * 10;
    const float* w5b = Wd5 + ((size_t)(lB * 128 + c)) * 10;
    float acc[10];
    #pragma unroll
    for (int o = 0; o < 10; ++o)
        acc[o] = a0 * w5a[o] + a1 * w5b[o];
    #pragma unroll
    for (int o = 0; o < 10; ++o)
        #pragma unroll
        for (int s = 32; s > 0; s >>= 1)
            acc[o] += __shfl_down(acc[o], s, 64);
    __shared__ float wred[8][10];
    int lane = threadIdx.x & 63, w = threadIdx.x >> 6;
    if (lane == 0) {
        #pragma unroll
        for (int o = 0; o < 10; ++o) wred[w][o] = acc[o];
    }
    __syncthreads();
    if (threadIdx.x < 10) {
        float v = 0.f;
        #pragma unroll
        for (int ww = 0; ww < 8; ++ww) v += wred[ww][threadIdx.x];
        atomicAdd(&out[b * 10 + threadIdx.x], v);
    }
}

extern "C" void kernel_launch(void* const* d_in, const int* in_sizes, int n_in,
                              void* d_out, int out_size, void* d_ws, size_t ws_size,
                              hipStream_t stream) {
    const int*   word = (const int*)d_in[0];
    const int*   pos  = (const int*)d_in[1];
    // d_in[2] = sentence_length (unused by reference)
    const float* wemb = (const float*)d_in[3];
    const float* pemb = (const float*)d_in[4];
    const float* Wdw1 = (const float*)d_in[5];
    const float* bdw1 = (const float*)d_in[6];
    const float* Wdw2 = (const float*)d_in[7];
    const float* bdw2 = (const float*)d_in[8];
    const float* Wdu1 = (const float*)d_in[9];
    const float* bdu1 = (const float*)d_in[10];
    const float* Wdu2 = (const float*)d_in[11];
    const float* bdu2 = (const float*)d_in[12];
    const float* Wd4  = (const float*)d_in[13];
    const float* bd4  = (const float*)d_in[14];
    const float* Wd5  = (const float*)d_in[15];

    float* ws    = (float*)d_ws;
    float* W4    = ws;                 // 128*640 = 81920
    float* bias4 = ws + 81920;         // 640
    float* pqrs  = ws + 82560;         // 2048*640 = 1310720
    float* sent  = ws + 1393280;       // 262144
    float* out   = (float*)d_out;

    k12_w4 <<<256, 1024, 0, stream>>>(Wdw1, Wdu1, Wdw2, Wdu2,
                                      bdw1, bdw2, bdu1, bdu2, W4, bias4, out);
    k3_pqrs<<<256,  640, 0, stream>>>(word, pos, wemb, pemb, W4, bias4, pqrs);
    k4_sent<<<512,  256, 0, stream>>>(pqrs, sent);
    k5_out <<<256,  512, 0, stream>>>(sent, Wd4, bd4, Wd5, out);
}